// Round 8
// baseline (266.140 us; speedup 1.0000x reference)
//
#include <hip/hip_runtime.h>
#include <hip/hip_cooperative_groups.h>
#include <stdint.h>

namespace cg = cooperative_groups;

#define CN 144
#define VN 576
#define BN 1024
#define NITER 3
#define RCAP 40      // row-weight capacity, multiple of 4 (actual max ~28)
#define NQ   (RCAP/4)
#define CCAP 8       // column-weight capacity (actual 4)
#define TPB 192      // 3 waves; 576/192 = exactly 3 columns per thread

// ws layout (ints):
#define WS_RLEN 0                    // [0,144)  row lengths
#define WS_LOC  192                  // [+CN*VN)  loc[v*CN+c] = slot in row, -1 if none
#define WS_CSC  (192 + CN*VN)        // [+CCAP*VN) slot-major [j][v] = edge id
#define WS_CCNT (WS_CSC + CCAP*VN)   // [+VN)

// edge id for (row-slot l, check c), quad layout: float index
// ((l>>2)*CN + c)*4 + (l&3) -> lane-consecutive float4 per (l>>2, c)
__device__ __forceinline__ int edge_id(int l, int c) {
    return (((l >> 2) * CN + c) << 2) | (l & 3);
}

__global__ __launch_bounds__(TPB, 3) void ldpc_fused(const float* __restrict__ r,
                                                     const float* __restrict__ alpha,
                                                     const float* __restrict__ H,
                                                     int* __restrict__ ws,
                                                     float* __restrict__ out) {
    __shared__ float4 M4[NQ * CN];
    float* const Mf = reinterpret_cast<float*>(M4);

    const int b = blockIdx.x;
    const int t = threadIdx.x;
    cg::grid_group grid = cg::this_grid();

    // prefetch r (independent of ws): HBM latency hides under build phases
    float rv[3];
    #pragma unroll
    for (int q = 0; q < 3; ++q) rv[q] = r[b * VN + t + q * TPB];
    const float a_[NITER] = { alpha[0], alpha[1], alpha[2] };

    // ---- phase 1: per-row ballot compaction -> transposed loc + row lengths ----
    if (b < CN && t < 64) {
        const int c = b;
        int base = 0;
        const float* row = H + c * VN;
        for (int ch = 0; ch < VN / 64; ++ch) {
            const int v = ch * 64 + t;
            const bool set = row[v] > 0.5f;
            const unsigned long long mask = __ballot(set);
            const int off = base + (int)__popcll(mask & ((1ULL << t) - 1ULL));
            ws[WS_LOC + v * CN + c] = set ? off : -1;   // ascending-v slot order
            base += (int)__popcll(mask);
        }
        if (t == 0) ws[WS_RLEN + c] = base;
    }
    grid.sync();

    // ---- phase 2: per-column ballot compaction into slot-major CSC ----
    if (b < VN && t < 64) {
        const int v = b, lane = t;
        int cnt = 0;
        for (int ch = 0; ch < 3; ++ch) {
            const int c = ch * 64 + lane;
            const int l = (c < CN) ? ws[WS_LOC + v * CN + c] : -1;   // coalesced
            const bool set = (l >= 0) && (l < RCAP);
            const unsigned long long mask = __ballot(set);
            const int off = cnt + (int)__popcll(mask & ((1ULL << lane) - 1ULL));
            if (set && off < CCAP) ws[WS_CSC + off * VN + v] = edge_id(l, c);
            cnt += (int)__popcll(mask);
        }
        if (cnt > CCAP) cnt = CCAP;
        if (lane == 0) ws[WS_CCNT + v] = cnt;
        if (lane >= cnt && lane < CCAP) ws[WS_CSC + lane * VN + v] = 0;  // defined, unused
    }
    grid.sync();

    // ---- phase 3: decode (R5-proven body), one block per batch item ----
    int ent4[3][4], entX[3][4];
    int cnt[3];
    #pragma unroll
    for (int q = 0; q < 3; ++q) {
        const int v = t + q * TPB;
        cnt[q] = ws[WS_CCNT + v];
        #pragma unroll
        for (int j = 0; j < 4; ++j) ent4[q][j] = ws[WS_CSC + j * VN + v];
    }
    const int rl = (t < CN) ? min(ws[WS_RLEN + t], RCAP) : 0;
    const int any_hi = __syncthreads_or((cnt[0] > 4) | (cnt[1] > 4) | (cnt[2] > 4));
    if (any_hi) {
        #pragma unroll
        for (int q = 0; q < 3; ++q)
            #pragma unroll
            for (int j = 0; j < 4; ++j) entX[q][j] = ws[WS_CSC + (4 + j) * VN + t + q * TPB];
    }

    // INF pads up to quad boundary (preserved across iterations)
    if (t < CN) {
        const int rpad = (rl + 3) & ~3;
        for (int k = rl; k < rpad; ++k) Mf[edge_id(k, t)] = INFINITY;
    }
    // M init = r on real edges (disjoint from pads)
    #pragma unroll
    for (int q = 0; q < 3; ++q) {
        #pragma unroll
        for (int j = 0; j < 4; ++j) if (j < cnt[q]) Mf[ent4[q][j]] = rv[q];
    }
    if (any_hi) {
        #pragma unroll
        for (int q = 0; q < 3; ++q) {
            #pragma unroll
            for (int j = 0; j < 4; ++j) if (4 + j < cnt[q]) Mf[entX[q][j]] = rv[q];
        }
    }
    __syncthreads();

    #pragma unroll
    for (int it = 0; it < NITER; ++it) {
        const float a = a_[it];

        // Pass A: two-loop min1/min2/first-argmin/sign (uint tricks), then E in place
        if (t < CN) {
            uint32_t m1 = 0x7fffffffu, m2 = 0x7fffffffu, sg = 0u;
            int am = 0;
            const int nq = (rl + 3) >> 2;
            for (int q4 = 0; q4 < nq; ++q4) {
                const float4 mv = M4[q4 * CN + t];
                const float* mp = reinterpret_cast<const float*>(&mv);
                #pragma unroll
                for (int j = 0; j < 4; ++j) {
                    const uint32_t mb = __float_as_uint(mp[j]);
                    const uint32_t ab = mb & 0x7fffffffu;   // INF pads never win
                    sg ^= mb;
                    const bool lt = ab < m1;                // strict: first occurrence
                    m2 = lt ? m1 : ((ab < m2) ? ab : m2);
                    m1 = lt ? ab : m1;
                    am = lt ? (q4 * 4 + j) : am;
                }
            }
            sg &= 0x80000000u;                              // pads are +INF: sign +1
            const uint32_t p1b = __float_as_uint(a * __uint_as_float(m1)) ^ sg;
            const uint32_t p2b = __float_as_uint(a * __uint_as_float(m2)) ^ sg;

            const int nqf = rl >> 2;                        // full quads: unpredicated
            for (int q4 = 0; q4 < nqf; ++q4) {
                const float4 mv = M4[q4 * CN + t];
                const float* mp = reinterpret_cast<const float*>(&mv);
                float4 ev;
                float* ep = reinterpret_cast<float*>(&ev);
                #pragma unroll
                for (int j = 0; j < 4; ++j) {
                    const uint32_t mb = __float_as_uint(mp[j]);
                    const uint32_t ps = ((q4 * 4 + j) == am) ? p2b : p1b;
                    ep[j] = __uint_as_float(ps ^ (mb & 0x80000000u));
                }
                M4[q4 * CN + t] = ev;
            }
            if (rl & 3) {                                   // tail quad: preserve INF pads
                const int q4 = nqf;
                const float4 mv = M4[q4 * CN + t];
                const float* mp = reinterpret_cast<const float*>(&mv);
                float4 ev;
                float* ep = reinterpret_cast<float*>(&ev);
                #pragma unroll
                for (int j = 0; j < 4; ++j) {
                    const int k = q4 * 4 + j;
                    const uint32_t mb = __float_as_uint(mp[j]);
                    const uint32_t ps = (k == am) ? p2b : p1b;
                    ep[j] = (k < rl) ? __uint_as_float(ps ^ (mb & 0x80000000u))
                                     : mp[j];
                }
                M4[q4 * CN + t] = ev;
            }
        }
        __syncthreads();

        // Pass B: per-column gather of E (ascending-c order), col-sum, fused M update
        #pragma unroll
        for (int q = 0; q < 3; ++q) {
            float E4[4], EX[4];
            float col = 0.0f;
            #pragma unroll
            for (int j = 0; j < 4; ++j) {
                E4[j] = (j < cnt[q]) ? Mf[ent4[q][j]] : 0.0f;
                col += E4[j];
            }
            if (any_hi) {
                #pragma unroll
                for (int j = 0; j < 4; ++j) {
                    EX[j] = (4 + j < cnt[q]) ? Mf[entX[q][j]] : 0.0f;
                    col += EX[j];
                }
            }
            if (it == NITER - 1) {
                out[b * VN + t + q * TPB] = rv[q] + col;
            } else {
                const float mb = col + rv[q];
                #pragma unroll
                for (int j = 0; j < 4; ++j) if (j < cnt[q]) Mf[ent4[q][j]] = mb - E4[j];
                if (any_hi) {
                    #pragma unroll
                    for (int j = 0; j < 4; ++j) if (4 + j < cnt[q]) Mf[entX[q][j]] = mb - EX[j];
                }
            }
        }
        if (it < NITER - 1) __syncthreads();
    }
}

extern "C" void kernel_launch(void* const* d_in, const int* in_sizes, int n_in,
                              void* d_out, int out_size, void* d_ws, size_t ws_size,
                              hipStream_t stream) {
    const float* r     = (const float*)d_in[0];
    const float* alpha = (const float*)d_in[1];
    const float* H     = (const float*)d_in[2];
    float* out = (float*)d_out;
    int* ws    = (int*)d_ws;

    void* kargs[] = { (void*)&r, (void*)&alpha, (void*)&H, (void*)&ws, (void*)&out };
    hipLaunchCooperativeKernel((const void*)ldpc_fused, dim3(BN), dim3(TPB),
                               kargs, 0, stream);
}

// Round 9
// 32.860 us; speedup vs baseline: 8.0992x; 8.0992x over previous
//
#include <hip/hip_runtime.h>
#include <stdint.h>

#define CN 144
#define VN 576
#define BN 1024
#define NITER 3
#define RCAP 32      // row-weight capacity (actual max ~28)
#define CCAP 8       // column-weight capacity (actual 4)
#define TPB 192      // 3 waves; 576/192 = exactly 3 columns per thread
#define BPB 4        // batches per block (float4-packed messages)

// ws layout (ints):
#define WS_RLEN 0                    // [0,144)  row lengths
#define WS_LOC  192                  // [+CN*VN)  loc[v*CN+c] = slot in row, -1 if none
#define WS_CSC  (192 + CN*VN)        // [+CCAP*VN) slot-major [j][v] = edge id l*CN+c
#define WS_CCNT (WS_CSC + CCAP*VN)   // [+VN)

union F4 { float4 v; float f[4]; uint32_t u[4]; };

// ---- build 1 (R5-proven): per-row ballot compaction -> loc + row lengths ----
__global__ __launch_bounds__(64) void build_stage(const float* __restrict__ H,
                                                  int* __restrict__ ws) {
    const int c = blockIdx.x;          // 144 blocks
    const int lane = threadIdx.x;      // 64
    int base = 0;
    const float* row = H + c * VN;
    for (int ch = 0; ch < VN / 64; ++ch) {
        const int v = ch * 64 + lane;
        const bool set = row[v] > 0.5f;
        const unsigned long long mask = __ballot(set);
        const int off = base + (int)__popcll(mask & ((1ULL << lane) - 1ULL));
        ws[WS_LOC + v * CN + c] = set ? off : -1;   // ascending-v slot order
        base += (int)__popcll(mask);
    }
    if (lane == 0) ws[WS_RLEN + c] = base;
}

// ---- build 2 (R5-proven): one wave per column -> slot-major CSC, edge = l*CN+c ----
__global__ __launch_bounds__(64) void build_csc(int* __restrict__ ws) {
    const int v = blockIdx.x;          // 576 blocks
    const int lane = threadIdx.x;      // 64
    int cnt = 0;
    for (int ch = 0; ch < 3; ++ch) {
        const int c = ch * 64 + lane;
        const int l = (c < CN) ? ws[WS_LOC + v * CN + c] : -1;   // coalesced
        const bool set = (l >= 0) && (l < RCAP);
        const unsigned long long mask = __ballot(set);
        const int off = cnt + (int)__popcll(mask & ((1ULL << lane) - 1ULL));
        if (set && off < CCAP) ws[WS_CSC + off * VN + v] = l * CN + c;
        cnt += (int)__popcll(mask);
    }
    if (cnt > CCAP) cnt = CCAP;
    if (lane == 0) ws[WS_CCNT + v] = cnt;
    if (lane >= cnt && lane < CCAP) ws[WS_CSC + lane * VN + v] = 0;  // defined, unused
}

// ---- decode: 4 batches per block, float4 messages; 256 blocks ----
__global__ __launch_bounds__(TPB) void ldpc_decode4(const float* __restrict__ r,
                                                    const float* __restrict__ alpha,
                                                    const int* __restrict__ ws,
                                                    float* __restrict__ out) {
    __shared__ float4 M4[RCAP * CN];   // 73.7 KB; edge e = l*CN + c

    const int b4 = blockIdx.x * BPB;   // first batch of this block
    const int t = threadIdx.x;
    const float a_[NITER] = { alpha[0], alpha[1], alpha[2] };

    // per-thread columns v = t + q*TPB: r for 4 batches + CSC
    int ent4[3][4], entX[3][4];
    int cnt[3];
    F4  rv[3];
    #pragma unroll
    for (int q = 0; q < 3; ++q) {
        const int v = t + q * TPB;
        #pragma unroll
        for (int s = 0; s < BPB; ++s) rv[q].f[s] = r[(b4 + s) * VN + v];
        cnt[q] = ws[WS_CCNT + v];
        #pragma unroll
        for (int j = 0; j < 4; ++j) ent4[q][j] = ws[WS_CSC + j * VN + v];
    }
    const int rl = (t < CN) ? min(ws[WS_RLEN + t], RCAP) : 0;
    const int any_hi = __syncthreads_or((cnt[0] > 4) | (cnt[1] > 4) | (cnt[2] > 4));
    if (any_hi) {
        #pragma unroll
        for (int q = 0; q < 3; ++q)
            #pragma unroll
            for (int j = 0; j < 4; ++j) entX[q][j] = ws[WS_CSC + (4 + j) * VN + t + q * TPB];
    }

    // M init = r on edges (every slot l<rl of every check is a real edge; no pads)
    #pragma unroll
    for (int q = 0; q < 3; ++q) {
        #pragma unroll
        for (int j = 0; j < 4; ++j) if (j < cnt[q]) M4[ent4[q][j]] = rv[q].v;
    }
    if (any_hi) {
        #pragma unroll
        for (int q = 0; q < 3; ++q) {
            #pragma unroll
            for (int j = 0; j < 4; ++j) if (4 + j < cnt[q]) M4[entX[q][j]] = rv[q].v;
        }
    }
    __syncthreads();

    #pragma unroll
    for (int it = 0; it < NITER; ++it) {
        const float a = a_[it];

        // Pass A: componentwise min1/min2/first-argmin/sign over 4 batches,
        // lane-consecutive b128 reads; then E written in place (two-loop, low VGPR).
        if (t < CN) {
            uint32_t m1[BPB], m2[BPB], sg[BPB]; int am[BPB];
            #pragma unroll
            for (int s = 0; s < BPB; ++s) { m1[s] = 0x7fffffffu; m2[s] = 0x7fffffffu; sg[s] = 0u; am[s] = 0; }
            for (int l = 0; l < rl; ++l) {
                F4 mv; mv.v = M4[l * CN + t];
                #pragma unroll
                for (int s = 0; s < BPB; ++s) {
                    const uint32_t mb = mv.u[s];
                    const uint32_t ab = mb & 0x7fffffffu;
                    sg[s] ^= mb;
                    const bool lt = ab < m1[s];            // strict: first occurrence
                    m2[s] = lt ? m1[s] : ((ab < m2[s]) ? ab : m2[s]);
                    m1[s] = lt ? ab : m1[s];
                    am[s] = lt ? l : am[s];
                }
            }
            uint32_t p1b[BPB], p2b[BPB];
            #pragma unroll
            for (int s = 0; s < BPB; ++s) {
                const uint32_t sgn = sg[s] & 0x80000000u;
                p1b[s] = __float_as_uint(a * __uint_as_float(m1[s])) ^ sgn;
                p2b[s] = __float_as_uint(a * __uint_as_float(m2[s])) ^ sgn;
            }
            for (int l = 0; l < rl; ++l) {
                F4 mv; mv.v = M4[l * CN + t];
                F4 ev;
                #pragma unroll
                for (int s = 0; s < BPB; ++s) {
                    const uint32_t ps = (l == am[s]) ? p2b[s] : p1b[s];
                    ev.u[s] = ps ^ (mv.u[s] & 0x80000000u);
                }
                M4[l * CN + t] = ev.v;
            }
        }
        __syncthreads();

        // Pass B: per-column b128 gather of E (ascending c), col-sum, fused M update
        #pragma unroll
        for (int q = 0; q < 3; ++q) {
            F4 E4[4], EX[4];
            F4 col; col.v = make_float4(0.f, 0.f, 0.f, 0.f);
            #pragma unroll
            for (int j = 0; j < 4; ++j) {
                if (j < cnt[q]) E4[j].v = M4[ent4[q][j]];
                else            E4[j].v = make_float4(0.f, 0.f, 0.f, 0.f);
                col.v += E4[j].v;
            }
            if (any_hi) {
                #pragma unroll
                for (int j = 0; j < 4; ++j) {
                    if (4 + j < cnt[q]) EX[j].v = M4[entX[q][j]];
                    else                EX[j].v = make_float4(0.f, 0.f, 0.f, 0.f);
                    col.v += EX[j].v;
                }
            }
            if (it == NITER - 1) {
                const int v = t + q * TPB;
                #pragma unroll
                for (int s = 0; s < BPB; ++s) out[(b4 + s) * VN + v] = rv[q].f[s] + col.f[s];
            } else {
                F4 mb; mb.v = col.v + rv[q].v;
                #pragma unroll
                for (int j = 0; j < 4; ++j)
                    if (j < cnt[q]) M4[ent4[q][j]] = mb.v - E4[j].v;
                if (any_hi) {
                    #pragma unroll
                    for (int j = 0; j < 4; ++j)
                        if (4 + j < cnt[q]) M4[entX[q][j]] = mb.v - EX[j].v;
                }
            }
        }
        if (it < NITER - 1) __syncthreads();
    }
}

extern "C" void kernel_launch(void* const* d_in, const int* in_sizes, int n_in,
                              void* d_out, int out_size, void* d_ws, size_t ws_size,
                              hipStream_t stream) {
    const float* r     = (const float*)d_in[0];
    const float* alpha = (const float*)d_in[1];
    const float* H     = (const float*)d_in[2];
    float* out = (float*)d_out;
    int* ws    = (int*)d_ws;

    build_stage<<<CN, 64, 0, stream>>>(H, ws);
    build_csc<<<VN, 64, 0, stream>>>(ws);
    ldpc_decode4<<<BN / BPB, TPB, 0, stream>>>(r, alpha, ws, out);
}

// Round 10
// 30.037 us; speedup vs baseline: 8.8603x; 1.0940x over previous
//
#include <hip/hip_runtime.h>
#include <stdint.h>

#define CN 144
#define VN 576
#define BN 1024
#define NITER 3
#define RCAP 32      // row-weight capacity, multiple of 4 (actual max ~28)
#define NQ   (RCAP/4)
#define CCAP 8       // column-weight capacity (actual 4)
#define TPB 384      // 6 waves/block -> 24 waves/CU at 4 blocks/CU

// ws layout (ints):
#define WS_RLEN 0          // [0,144)   row lengths
#define WS_CCNT 144        // [144,720) per-column edge counts (memset to 0 each call)
#define WS_CSC  720        // [720, 720+CCAP*VN) slot-major [j][v] = edge id

// edge id for (row-slot l, check c), quad layout: float index
// ((l>>2)*CN + c)*4 + (l&3) -> lane-consecutive float4 per (l>>2, c)
__device__ __forceinline__ int edge_id(int l, int c) {
    return (((l >> 2) * CN + c) << 2) | (l & 3);
}

// ---- build: per-row ballot compaction + atomic append into per-column CSC ----
// Column order within a CSC list is arbitrary (atomic): col-sum order only
// perturbs fp rounding (~1e-6 << 9.4e-2 threshold); |M| ties make the argmin
// slot choice value-irrelevant (min1==min2 -> same E), so slot/list order is free.
__global__ __launch_bounds__(64) void build_all(const float* __restrict__ H,
                                                int* __restrict__ ws) {
    const int c = blockIdx.x;          // 144 blocks
    const int lane = threadIdx.x;      // 64
    int base = 0;
    const float* row = H + c * VN;
    for (int ch = 0; ch < VN / 64; ++ch) {
        const int v = ch * 64 + lane;
        const bool set = row[v] > 0.5f;
        const unsigned long long mask = __ballot(set);
        const int l = base + (int)__popcll(mask & ((1ULL << lane) - 1ULL));
        if (set && l < RCAP) {
            const int pos = atomicAdd(ws + WS_CCNT + v, 1);
            if (pos < CCAP) ws[WS_CSC + pos * VN + v] = edge_id(l, c);
        }
        base += (int)__popcll(mask);
    }
    if (lane == 0) ws[WS_RLEN + c] = base;
}

// ---- decode: one block per batch item; R5-proven body at TPB=384 ----
__global__ __launch_bounds__(TPB) void ldpc_decode(const float* __restrict__ r,
                                                   const float* __restrict__ alpha,
                                                   const int* __restrict__ ws,
                                                   float* __restrict__ out) {
    __shared__ float4 M4[NQ * CN];     // 18.4 KB
    float* const Mf = reinterpret_cast<float*>(M4);

    const int b = blockIdx.x;
    const int t = threadIdx.x;
    const float a_[NITER] = { alpha[0], alpha[1], alpha[2] };

    // thread t owns col v0 = t (always) and v1 = 384+t (if t < 192)
    const bool has2 = (t < VN - TPB);
    const int v0 = t, v1 = TPB + t;
    const float rv0 = r[b * VN + v0];
    const float rv1 = has2 ? r[b * VN + v1] : 0.0f;
    const int cnt0 = min(ws[WS_CCNT + v0], CCAP);
    const int cnt1 = has2 ? min(ws[WS_CCNT + v1], CCAP) : 0;
    int ent0[4], ent1[4], entX0[4], entX1[4];
    #pragma unroll
    for (int j = 0; j < 4; ++j) {
        ent0[j] = ws[WS_CSC + j * VN + v0];
        ent1[j] = has2 ? ws[WS_CSC + j * VN + v1] : 0;
    }
    const int rl = (t < CN) ? min(ws[WS_RLEN + t], RCAP) : 0;
    const int any_hi = __syncthreads_or((cnt0 > 4) | (cnt1 > 4));
    if (any_hi) {
        #pragma unroll
        for (int j = 0; j < 4; ++j) {
            entX0[j] = ws[WS_CSC + (4 + j) * VN + v0];
            entX1[j] = has2 ? ws[WS_CSC + (4 + j) * VN + v1] : 0;
        }
    }

    // INF pads up to quad boundary (preserved across iterations)
    if (t < CN) {
        const int rpad = (rl + 3) & ~3;
        for (int k = rl; k < rpad; ++k) Mf[edge_id(k, t)] = INFINITY;
    }
    // M init = r on real edges (disjoint from pads)
    #pragma unroll
    for (int j = 0; j < 4; ++j) {
        if (j < cnt0) Mf[ent0[j]] = rv0;
        if (j < cnt1) Mf[ent1[j]] = rv1;
    }
    if (any_hi) {
        #pragma unroll
        for (int j = 0; j < 4; ++j) {
            if (4 + j < cnt0) Mf[entX0[j]] = rv0;
            if (4 + j < cnt1) Mf[entX1[j]] = rv1;
        }
    }
    __syncthreads();

    #pragma unroll
    for (int it = 0; it < NITER; ++it) {
        const float a = a_[it];

        // Pass A: two-loop min1/min2/first-argmin/sign (uint tricks), E in place
        if (t < CN) {
            uint32_t m1 = 0x7fffffffu, m2 = 0x7fffffffu, sg = 0u;
            int am = 0;
            const int nq = (rl + 3) >> 2;
            for (int q4 = 0; q4 < nq; ++q4) {
                const float4 mv = M4[q4 * CN + t];
                const float* mp = reinterpret_cast<const float*>(&mv);
                #pragma unroll
                for (int j = 0; j < 4; ++j) {
                    const uint32_t mb = __float_as_uint(mp[j]);
                    const uint32_t ab = mb & 0x7fffffffu;   // INF pads never win
                    sg ^= mb;
                    const bool lt = ab < m1;
                    m2 = lt ? m1 : ((ab < m2) ? ab : m2);
                    m1 = lt ? ab : m1;
                    am = lt ? (q4 * 4 + j) : am;
                }
            }
            sg &= 0x80000000u;                              // pads are +INF: sign +1
            const uint32_t p1b = __float_as_uint(a * __uint_as_float(m1)) ^ sg;
            const uint32_t p2b = __float_as_uint(a * __uint_as_float(m2)) ^ sg;

            const int nqf = rl >> 2;                        // full quads
            for (int q4 = 0; q4 < nqf; ++q4) {
                const float4 mv = M4[q4 * CN + t];
                const float* mp = reinterpret_cast<const float*>(&mv);
                float4 ev;
                float* ep = reinterpret_cast<float*>(&ev);
                #pragma unroll
                for (int j = 0; j < 4; ++j) {
                    const uint32_t mb = __float_as_uint(mp[j]);
                    const uint32_t ps = ((q4 * 4 + j) == am) ? p2b : p1b;
                    ep[j] = __uint_as_float(ps ^ (mb & 0x80000000u));
                }
                M4[q4 * CN + t] = ev;
            }
            if (rl & 3) {                                   // tail quad: keep INF pads
                const int q4 = nqf;
                const float4 mv = M4[q4 * CN + t];
                const float* mp = reinterpret_cast<const float*>(&mv);
                float4 ev;
                float* ep = reinterpret_cast<float*>(&ev);
                #pragma unroll
                for (int j = 0; j < 4; ++j) {
                    const int k = q4 * 4 + j;
                    const uint32_t mb = __float_as_uint(mp[j]);
                    const uint32_t ps = (k == am) ? p2b : p1b;
                    ep[j] = (k < rl) ? __uint_as_float(ps ^ (mb & 0x80000000u))
                                     : mp[j];
                }
                M4[q4 * CN + t] = ev;
            }
        }
        __syncthreads();

        // Pass B: per-column gather of E, col-sum, fused M update
        {
            float E0[4], E1[4], X0[4], X1[4];
            float col0 = 0.0f, col1 = 0.0f;
            #pragma unroll
            for (int j = 0; j < 4; ++j) {
                E0[j] = (j < cnt0) ? Mf[ent0[j]] : 0.0f;  col0 += E0[j];
                E1[j] = (j < cnt1) ? Mf[ent1[j]] : 0.0f;  col1 += E1[j];
            }
            if (any_hi) {
                #pragma unroll
                for (int j = 0; j < 4; ++j) {
                    X0[j] = (4 + j < cnt0) ? Mf[entX0[j]] : 0.0f;  col0 += X0[j];
                    X1[j] = (4 + j < cnt1) ? Mf[entX1[j]] : 0.0f;  col1 += X1[j];
                }
            }
            if (it == NITER - 1) {
                out[b * VN + v0] = rv0 + col0;
                if (has2) out[b * VN + v1] = rv1 + col1;
            } else {
                const float mb0 = col0 + rv0;
                const float mb1 = col1 + rv1;
                #pragma unroll
                for (int j = 0; j < 4; ++j) {
                    if (j < cnt0) Mf[ent0[j]] = mb0 - E0[j];
                    if (j < cnt1) Mf[ent1[j]] = mb1 - E1[j];
                }
                if (any_hi) {
                    #pragma unroll
                    for (int j = 0; j < 4; ++j) {
                        if (4 + j < cnt0) Mf[entX0[j]] = mb0 - X0[j];
                        if (4 + j < cnt1) Mf[entX1[j]] = mb1 - X1[j];
                    }
                }
            }
        }
        if (it < NITER - 1) __syncthreads();
    }
}

extern "C" void kernel_launch(void* const* d_in, const int* in_sizes, int n_in,
                              void* d_out, int out_size, void* d_ws, size_t ws_size,
                              hipStream_t stream) {
    const float* r     = (const float*)d_in[0];
    const float* alpha = (const float*)d_in[1];
    const float* H     = (const float*)d_in[2];
    float* out = (float*)d_out;
    int* ws    = (int*)d_ws;

    hipMemsetAsync(ws + WS_CCNT, 0, VN * sizeof(int), stream);   // zero column counters
    build_all<<<CN, 64, 0, stream>>>(H, ws);
    ldpc_decode<<<BN, TPB, 0, stream>>>(r, alpha, ws, out);
}

// Round 11
// 23.728 us; speedup vs baseline: 11.2164x; 1.2659x over previous
//
#include <hip/hip_runtime.h>
#include <stdint.h>

#define CN 144
#define VN 576
#define BN 1024
#define NITER 3
#define RCAP 32      // row-weight capacity, multiple of 4 (actual max ~28; R9/R10-proven)
#define NQ   (RCAP/4)
#define CCAP 8       // column-weight capacity (actual 4)
#define TPB 192      // 3 waves; 576/192 = exactly 3 columns per thread

// ws layout (ints):
#define WS_RLEN 0                    // [0,144)  row lengths
#define WS_LOC  192                  // [+CN*VN)  loc[v*CN+c] = slot in row, -1 if none
#define WS_CSC  (192 + CN*VN)        // [+CCAP*VN) slot-major [j][v] = edge id
#define WS_CCNT (WS_CSC + CCAP*VN)   // [+VN)

// edge id for (row-slot l, check c), quad layout: float index
// ((l>>2)*CN + c)*4 + (l&3) -> lane-consecutive float4 per (l>>2, c)
__device__ __forceinline__ int edge_id(int l, int c) {
    return (((l >> 2) * CN + c) << 2) | (l & 3);
}

// ---- build 1 (R5-proven): per-row ballot compaction -> loc + row lengths ----
__global__ __launch_bounds__(64) void build_stage(const float* __restrict__ H,
                                                  int* __restrict__ ws) {
    const int c = blockIdx.x;          // 144 blocks
    const int lane = threadIdx.x;      // 64
    int base = 0;
    const float* row = H + c * VN;
    for (int ch = 0; ch < VN / 64; ++ch) {
        const int v = ch * 64 + lane;
        const bool set = row[v] > 0.5f;
        const unsigned long long mask = __ballot(set);
        const int off = base + (int)__popcll(mask & ((1ULL << lane) - 1ULL));
        ws[WS_LOC + v * CN + c] = set ? off : -1;   // ascending-v slot order
        base += (int)__popcll(mask);
    }
    if (lane == 0) ws[WS_RLEN + c] = base;
}

// ---- build 2 (R5-proven): one wave per column -> slot-major CSC ----
__global__ __launch_bounds__(64) void build_csc(int* __restrict__ ws) {
    const int v = blockIdx.x;          // 576 blocks
    const int lane = threadIdx.x;      // 64
    int cnt = 0;
    for (int ch = 0; ch < 3; ++ch) {
        const int c = ch * 64 + lane;
        const int l = (c < CN) ? ws[WS_LOC + v * CN + c] : -1;   // coalesced
        const bool set = (l >= 0) && (l < RCAP);
        const unsigned long long mask = __ballot(set);
        const int off = cnt + (int)__popcll(mask & ((1ULL << lane) - 1ULL));
        if (set && off < CCAP) ws[WS_CSC + off * VN + v] = edge_id(l, c);
        cnt += (int)__popcll(mask);
    }
    if (cnt > CCAP) cnt = CCAP;
    if (lane == 0) ws[WS_CCNT + v] = cnt;
    if (lane >= cnt && lane < CCAP) ws[WS_CSC + lane * VN + v] = 0;  // defined, unused
}

// ---- decode: one block per batch item; R5 body + 5-op scan + reg-quad writeback ----
__global__ __launch_bounds__(TPB) void ldpc_decode(const float* __restrict__ r,
                                                   const float* __restrict__ alpha,
                                                   const int* __restrict__ ws,
                                                   float* __restrict__ out) {
    __shared__ float4 M4[NQ * CN];     // 18.4 KB
    float* const Mf = reinterpret_cast<float*>(M4);

    const int b = blockIdx.x;
    const int t = threadIdx.x;
    const float a_[NITER] = { alpha[0], alpha[1], alpha[2] };

    // per-thread columns v = t + q*TPB
    int ent4[3][4], entX[3][4];
    int cnt[3];
    float rv[3];
    #pragma unroll
    for (int q = 0; q < 3; ++q) {
        const int v = t + q * TPB;
        rv[q]  = r[b * VN + v];
        cnt[q] = ws[WS_CCNT + v];
        #pragma unroll
        for (int j = 0; j < 4; ++j) ent4[q][j] = ws[WS_CSC + j * VN + v];
    }
    const int rl = (t < CN) ? min(ws[WS_RLEN + t], RCAP) : 0;
    const int any_hi = __syncthreads_or((cnt[0] > 4) | (cnt[1] > 4) | (cnt[2] > 4));
    if (any_hi) {
        #pragma unroll
        for (int q = 0; q < 3; ++q)
            #pragma unroll
            for (int j = 0; j < 4; ++j) entX[q][j] = ws[WS_CSC + (4 + j) * VN + t + q * TPB];
    }

    // INF pads up to quad boundary (preserved across iterations)
    if (t < CN) {
        const int rpad = (rl + 3) & ~3;
        for (int k = rl; k < rpad; ++k) Mf[edge_id(k, t)] = INFINITY;
    }
    // M init = r on real edges (disjoint from pads)
    #pragma unroll
    for (int q = 0; q < 3; ++q) {
        #pragma unroll
        for (int j = 0; j < 4; ++j) if (j < cnt[q]) Mf[ent4[q][j]] = rv[q];
    }
    if (any_hi) {
        #pragma unroll
        for (int q = 0; q < 3; ++q) {
            #pragma unroll
            for (int j = 0; j < 4; ++j) if (4 + j < cnt[q]) Mf[entX[q][j]] = rv[q];
        }
    }
    __syncthreads();

    #pragma unroll
    for (int it = 0; it < NITER; ++it) {
        const float a = a_[it];

        // Pass A: 5-op two-smallest scan (no argmin), register-cached quads,
        // writeback E in place with equality-based exclusion (bit-exact, see proof).
        if (t < CN) {
            const int nq  = (rl + 3) >> 2;
            const int nqf = rl >> 2;
            float4 mq[NQ];                          // statically indexed (unrolled)
            uint32_t m1 = 0x7fffffffu, m2 = 0x7fffffffu, sg = 0u;
            #pragma unroll
            for (int q4 = 0; q4 < NQ; ++q4) {
                if (q4 < nq) {
                    mq[q4] = M4[q4 * CN + t];
                    const uint32_t* mu = reinterpret_cast<const uint32_t*>(&mq[q4]);
                    #pragma unroll
                    for (int j = 0; j < 4; ++j) {
                        const uint32_t mb = mu[j];
                        const uint32_t ab = mb & 0x7fffffffu;  // INF pads never win
                        sg ^= mb;
                        const uint32_t hi = (ab > m1) ? ab : m1;
                        m1 = (ab < m1) ? ab : m1;
                        m2 = (hi < m2) ? hi : m2;
                    }
                }
            }
            sg &= 0x80000000u;                              // pads are +INF: sign +1
            const uint32_t p1b = __float_as_uint(a * __uint_as_float(m1)) ^ sg;
            const uint32_t p2b = __float_as_uint(a * __uint_as_float(m2)) ^ sg;
            // exclusion by ab==m1: unique min -> exact argmin; ties -> m2==m1 so
            // p1b==p2b and the choice is value-irrelevant (matches jnp bit-exact)
            #pragma unroll
            for (int q4 = 0; q4 < NQ; ++q4) {
                if (q4 < nq) {
                    const uint32_t* mu = reinterpret_cast<const uint32_t*>(&mq[q4]);
                    float4 ev;
                    uint32_t* eu = reinterpret_cast<uint32_t*>(&ev);
                    if (q4 < nqf) {                         // full quad
                        #pragma unroll
                        for (int j = 0; j < 4; ++j) {
                            const uint32_t mb = mu[j];
                            const uint32_t ab = mb & 0x7fffffffu;
                            eu[j] = ((ab == m1) ? p2b : p1b) ^ (mb & 0x80000000u);
                        }
                    } else {                                // tail quad: keep INF pads
                        #pragma unroll
                        for (int j = 0; j < 4; ++j) {
                            const int k = q4 * 4 + j;
                            const uint32_t mb = mu[j];
                            const uint32_t ab = mb & 0x7fffffffu;
                            eu[j] = (k < rl)
                                  ? (((ab == m1) ? p2b : p1b) ^ (mb & 0x80000000u))
                                  : mb;
                        }
                    }
                    M4[q4 * CN + t] = ev;
                }
            }
        }
        __syncthreads();

        // Pass B: per-column gather of E (ascending c), col-sum, fused M update
        #pragma unroll
        for (int q = 0; q < 3; ++q) {
            float E4[4], EX[4];
            float col = 0.0f;
            #pragma unroll
            for (int j = 0; j < 4; ++j) {
                E4[j] = (j < cnt[q]) ? Mf[ent4[q][j]] : 0.0f;
                col += E4[j];
            }
            if (any_hi) {
                #pragma unroll
                for (int j = 0; j < 4; ++j) {
                    EX[j] = (4 + j < cnt[q]) ? Mf[entX[q][j]] : 0.0f;
                    col += EX[j];
                }
            }
            if (it == NITER - 1) {
                out[b * VN + t + q * TPB] = rv[q] + col;
            } else {
                const float mb = col + rv[q];
                #pragma unroll
                for (int j = 0; j < 4; ++j) if (j < cnt[q]) Mf[ent4[q][j]] = mb - E4[j];
                if (any_hi) {
                    #pragma unroll
                    for (int j = 0; j < 4; ++j) if (4 + j < cnt[q]) Mf[entX[q][j]] = mb - EX[j];
                }
            }
        }
        if (it < NITER - 1) __syncthreads();
    }
}

extern "C" void kernel_launch(void* const* d_in, const int* in_sizes, int n_in,
                              void* d_out, int out_size, void* d_ws, size_t ws_size,
                              hipStream_t stream) {
    const float* r     = (const float*)d_in[0];
    const float* alpha = (const float*)d_in[1];
    const float* H     = (const float*)d_in[2];
    float* out = (float*)d_out;
    int* ws    = (int*)d_ws;

    build_stage<<<CN, 64, 0, stream>>>(H, ws);
    build_csc<<<VN, 64, 0, stream>>>(ws);
    ldpc_decode<<<BN, TPB, 0, stream>>>(r, alpha, ws, out);
}